// Round 13
// baseline (138.806 us; speedup 1.0000x reference)
//
#include <hip/hip_runtime.h>

#define T_ 4
#define B_ 8
#define N_ 1024
#define C_ 512
#define H_ 8
#define D_ 64
#define M_ (T_*B_*N_)   // 32768 rows
#define TB_ (T_*B_)     // 32

typedef __bf16 bf16;
typedef __bf16 bf16x4 __attribute__((ext_vector_type(4)));
typedef __bf16 bf16x8 __attribute__((ext_vector_type(8)));
typedef float f32x4 __attribute__((ext_vector_type(4)));

__device__ __forceinline__ void gload16(const void* g, void* l) {
  __builtin_amdgcn_global_load_lds(
      (const __attribute__((address_space(1))) void*)g,
      (__attribute__((address_space(3))) void*)l, 16, 0, 0);
}

struct PtrPack { const float* p[24]; };

// =====================================================================
// cvt_prep: blocks [0,4096): x -> xT (bf16 transpose) + col-sum partials.
// blocks [4096,6144): fold BN into the 4 weight mats (+ bias vec).
// blocks [6144,6208): WqT[c][d] = Wq[d][c]*sq[d].
// =====================================================================
__global__ __launch_bounds__(256)
void cvt_prep(PtrPack pk, const float* __restrict__ x,
              bf16* __restrict__ xT, float* __restrict__ spart,
              bf16* __restrict__ WB, float* __restrict__ BS,
              bf16* __restrict__ WqT) {
  const int t = threadIdx.x;
  __shared__ __align__(16) char smem[21120];   // 64*65 f32 + 16*64 f32
  if (blockIdx.x < 4096) {
    const int bid = blockIdx.x;
    const int tb = bid >> 7, nc = (bid >> 3) & 15, cc = bid & 7;
    float* lds = (float*)smem;                 // [64][65]
    float* sred = (float*)smem + 4160;         // [16][64]
    const float* xbase = x + (size_t)tb * 524288 + (size_t)nc * 64 * 512 + cc * 64;
    bf16* xTb = xT + (size_t)tb * 524288 + (size_t)(cc * 64) * 1024 + nc * 64;
    const int rgrp = t >> 4, k = t & 15;
    float s0 = 0, s1 = 0, s2 = 0, s3 = 0;
#pragma unroll
    for (int p = 0; p < 4; p++) {
      int r = p * 16 + rgrp;
      float4 v = *(const float4*)(xbase + (size_t)r * 512 + k * 4);
      lds[r*65 + k*4+0]=v.x; lds[r*65 + k*4+1]=v.y;
      lds[r*65 + k*4+2]=v.z; lds[r*65 + k*4+3]=v.w;
      s0 += v.x; s1 += v.y; s2 += v.z; s3 += v.w;
    }
    sred[rgrp*64 + k*4+0]=s0; sred[rgrp*64 + k*4+1]=s1;
    sred[rgrp*64 + k*4+2]=s2; sred[rgrp*64 + k*4+3]=s3;
    __syncthreads();
#pragma unroll
    for (int p = 0; p < 16; p++) {
      int c = p * 4 + (t >> 6), n = t & 63;
      xTb[(size_t)c * 1024 + n] = (bf16)lds[n*65 + c];
    }
    if (t < 64) {
      float tot = 0;
#pragma unroll
      for (int rg = 0; rg < 16; rg++) tot += sred[rg*64 + t];
      spart[(size_t)((tb*8 + cc)*16 + nc) * 64 + t] = tot;
    }
    return;
  }
  if (blockIdx.x < 6144) {
    const int e = blockIdx.x - 4096;
    const int mat = e >> 9, d = e & 511;
    const float* W    = pk.p[6*mat + 0];
    const float* b    = pk.p[6*mat + 1];
    const float* g    = pk.p[6*mat + 2];
    const float* beta = pk.p[6*mat + 3];
    const float* mu   = pk.p[6*mat + 4];
    const float* var  = pk.p[6*mat + 5];
    float s = g[d] * rsqrtf(var[d] + 1e-5f);
    if (t == 0) BS[mat*512 + d] = (b[d] - mu[d]) * s + beta[d];
    bf16* Wout = WB + (size_t)mat * 262144 + (size_t)d * 512;
    for (int c = t; c < 512; c += 256)
      Wout[c] = (bf16)(W[(size_t)d * 512 + c] * s);
    return;
  }
  // WqT part
  const int e = blockIdx.x - 6144;
  const int di = e >> 3, ci = e & 7;
  float* lds = (float*)smem;   // [64][65]
  const float* W = pk.p[0];
  const float* g = pk.p[2];
  const float* var = pk.p[5];
  const int rgrp = t >> 4, k = t & 15;
#pragma unroll
  for (int p = 0; p < 4; p++) {
    int r = p * 16 + rgrp;
    int d = di * 64 + r;
    float s = g[d] * rsqrtf(var[d] + 1e-5f);
    float4 v = *(const float4*)(W + (size_t)d * 512 + ci * 64 + k * 4);
    lds[r*65 + k*4+0] = v.x * s; lds[r*65 + k*4+1] = v.y * s;
    lds[r*65 + k*4+2] = v.z * s; lds[r*65 + k*4+3] = v.w * s;
  }
  __syncthreads();
#pragma unroll
  for (int p = 0; p < 16; p++) {
    int c = p * 4 + (t >> 6), dd = t & 63;
    WqT[(size_t)(ci*64 + c) * 512 + di*64 + dd] = (bf16)lds[dd*65 + c];
  }
}

// =====================================================================
// gram_ksvs: blocks [0,640): SYM Gram G[tb] = xT xT^T, 64x128 tiles,
//   BK=128 (8 K-steps), triangular 20/32 set + mirror store via LDS.
// blocks [640,704): ksvs.
// =====================================================================
__global__ __launch_bounds__(256, 3)
void gram_ksvs(const bf16* __restrict__ xT, const bf16* __restrict__ WB,
               const float* __restrict__ spart, bf16* __restrict__ Gb,
               float* __restrict__ ksv) {
  const int t = threadIdx.x;
  __shared__ __align__(16) char smem[49152];   // As 16K + Bs 32K
  if (blockIdx.x >= 640) {
    const int e = blockIdx.x - 640, tb = e >> 1, m = e & 1;
    float* sl = (float*)smem;
#pragma unroll
    for (int half = 0; half < 2; half++) {
      int c = t + half * 256, cc = c >> 6, cl = c & 63;
      float tot = 0;
#pragma unroll
      for (int ncf = 0; ncf < 16; ncf++)
        tot += spart[(size_t)((tb*8 + cc)*16 + ncf) * 64 + cl];
      sl[c] = tot;
    }
    __syncthreads();
#pragma unroll
    for (int half = 0; half < 2; half++) {
      int d = t + half * 256;
      const bf16* Wrow = WB + (size_t)(m + 1) * 262144 + (size_t)d * 512;
      float acc = 0;
      for (int k = 0; k < 512; k += 8) {
        bf16x8 wv = *(const bf16x8*)(Wrow + k);
#pragma unroll
        for (int i = 0; i < 8; i++) acc += (float)wv[i] * sl[k + i];
      }
      ksv[m * 16384 + tb * 512 + d] = acc;
    }
    return;
  }
  constexpr int K = 1024;
  const int bid = blockIdx.x;
  const int xcd = bid & 7, j9 = bid >> 3;
  const int bat = xcd + 8 * (j9 / 20);
  const int tile = j9 % 20;
  int mi, ni;
  if (tile < 8)       { mi = tile;          ni = 0; }
  else if (tile < 14) { mi = tile - 8 + 2;  ni = 1; }
  else if (tile < 18) { mi = tile - 14 + 4; ni = 2; }
  else                { mi = tile - 18 + 6; ni = 3; }
  const bf16* A = xT + (size_t)bat * 524288;
  const int m0 = mi * 64, n0 = ni * 128;
  bf16* As = (bf16*)smem;               // [64][128]
  bf16* Bs = (bf16*)(smem + 16384);     // [128][128]
  const int w = t >> 6, l = t & 63;
  const int wm = w >> 1, wn = w & 1;
  const int lr = l & 15, lq = l >> 4;
  const int srow = l >> 4, schk = l & 15;
  f32x4 acc[2][4] = {};
  for (int kt = 0; kt < 8; kt++) {
#pragma unroll
    for (int i = 0; i < 4; i++) {
      int rb = w * 16 + i * 4, r = rb + srow;
      gload16(A + (size_t)(m0 + r) * K + kt*128 + ((schk ^ (r & 7)) * 8),
              As + rb * 128);
    }
#pragma unroll
    for (int i = 0; i < 8; i++) {
      int rb = w * 32 + i * 4, r = rb + srow;
      gload16(A + (size_t)(n0 + r) * K + kt*128 + ((schk ^ (r & 7)) * 8),
              Bs + rb * 128);
    }
    __syncthreads();
#pragma unroll
    for (int s = 0; s < 4; s++) {
      bf16x8 af[2], bv[4];
#pragma unroll
      for (int f = 0; f < 2; f++) {
        int ra = wm * 32 + f * 16 + lr;
        af[f] = *(const bf16x8*)&As[ra * 128 + (((s*4+lq) ^ (ra & 7)) * 8)];
      }
#pragma unroll
      for (int f = 0; f < 4; f++) {
        int rb2 = wn * 64 + f * 16 + lr;
        bv[f] = *(const bf16x8*)&Bs[rb2 * 128 + (((s*4+lq) ^ (rb2 & 7)) * 8)];
      }
#pragma unroll
      for (int mt = 0; mt < 2; mt++)
#pragma unroll
        for (int nt = 0; nt < 4; nt++)
          acc[mt][nt] = __builtin_amdgcn_mfma_f32_16x16x32_bf16(
              af[mt], bv[nt], acc[mt][nt], 0, 0, 0);
    }
    __syncthreads();
  }
  bf16* ob = Gb + (size_t)bat * 262144;
#pragma unroll
  for (int mt = 0; mt < 2; mt++)
#pragma unroll
    for (int nt = 0; nt < 4; nt++) {
      int j = n0 + wn * 64 + nt * 16 + lr;
      size_t mrow = (size_t)m0 + wm * 32 + mt * 16 + lq * 4;
#pragma unroll
      for (int r = 0; r < 4; r++)
        ob[(mrow + r) * 512 + j] = (bf16)acc[mt][nt][r];
    }
  bf16* TB = (bf16*)smem;   // [128][64]
#pragma unroll
  for (int mt = 0; mt < 2; mt++)
#pragma unroll
    for (int nt = 0; nt < 4; nt++) {
      int a = wn * 64 + nt * 16 + lr;
#pragma unroll
      for (int r = 0; r < 4; r++) {
        int b = wm * 32 + mt * 16 + lq * 4 + r;
        TB[(a * 64 + b) ^ ((a & 7) << 3)] = (bf16)acc[mt][nt][r];
      }
    }
  __syncthreads();
  const int rowa = t >> 1, half = t & 1;
#pragma unroll
  for (int i = 0; i < 4; i++) {
    int c8 = half * 4 + i;
    bf16x8 v = *(const bf16x8*)&TB[(rowa * 64 + c8 * 8) ^ ((rowa & 7) << 3)];
    *(bf16x8*)(ob + (size_t)(n0 + rowa) * 512 + m0 + c8 * 8) = v;
  }
}

// =====================================================================
// Batched 64x128-tile GEMM, BK=128 (NKT128 K-steps), 48 KB LDS,
// chunk-XOR swizzle, gload_lds staging, XCD-clustered batches.
// =====================================================================
template <int NKT128, int MTILES, bool BF16OUT, bool BIAS>
__global__ __launch_bounds__(256, 3)
void gemm_n(const bf16* __restrict__ Abase, size_t Astr,
            const bf16* __restrict__ Btbase, size_t Btstr,
            const float* __restrict__ BSb,
            bf16* __restrict__ ob, float* __restrict__ of, size_t Ostr) {
  constexpr int K = NKT128 * 128;
  constexpr int PERB = MTILES * 4;
  const int bid = blockIdx.x;
  const int xcd = bid & 7, j9 = bid >> 3;
  const int bat = xcd + 8 * (j9 / PERB);
  const int tile = j9 % PERB;
  const int mi = tile >> 2, ni = tile & 3;
  const bf16* A = Abase + (size_t)bat * Astr;
  const bf16* Bt = Btbase + (size_t)bat * Btstr;
  const int m0 = mi * 64, n0 = ni * 128;
  __shared__ __align__(16) bf16 As[64][128];    // 16 KB
  __shared__ __align__(16) bf16 Bs[128][128];   // 32 KB
  const int tid = threadIdx.x, w = tid >> 6, l = tid & 63;
  const int wm = w >> 1, wn = w & 1;
  const int lr = l & 15, lq = l >> 4;
  const int srow = l >> 4, schk = l & 15;
  f32x4 acc[2][4] = {};
  for (int kt = 0; kt < NKT128; kt++) {
#pragma unroll
    for (int i = 0; i < 4; i++) {
      int rb = w * 16 + i * 4, r = rb + srow;
      gload16(A + (size_t)(m0 + r) * K + kt*128 + ((schk ^ (r & 7)) * 8),
              &As[rb][0]);
    }
#pragma unroll
    for (int i = 0; i < 8; i++) {
      int rb = w * 32 + i * 4, r = rb + srow;
      gload16(Bt + (size_t)(n0 + r) * K + kt*128 + ((schk ^ (r & 7)) * 8),
              &Bs[rb][0]);
    }
    __syncthreads();
#pragma unroll
    for (int s = 0; s < 4; s++) {
      bf16x8 af[2], bv[4];
#pragma unroll
      for (int f = 0; f < 2; f++) {
        int ra = wm * 32 + f * 16 + lr;
        af[f] = *(const bf16x8*)&As[ra][((s*4+lq) ^ (ra & 7)) * 8];
      }
#pragma unroll
      for (int f = 0; f < 4; f++) {
        int rb2 = wn * 64 + f * 16 + lr;
        bv[f] = *(const bf16x8*)&Bs[rb2][((s*4+lq) ^ (rb2 & 7)) * 8];
      }
#pragma unroll
      for (int mt = 0; mt < 2; mt++)
#pragma unroll
        for (int nt = 0; nt < 4; nt++)
          acc[mt][nt] = __builtin_amdgcn_mfma_f32_16x16x32_bf16(
              af[mt], bv[nt], acc[mt][nt], 0, 0, 0);
    }
    __syncthreads();
  }

  float bja[4];
  if constexpr (BIAS) {
#pragma unroll
    for (int nt = 0; nt < 4; nt++) {
      int j = n0 + wn * 64 + nt * 16 + lr;
      bja[nt] = BSb[(size_t)bat * 512 + j];
    }
  }
#pragma unroll
  for (int mt = 0; mt < 2; mt++)
#pragma unroll
    for (int nt = 0; nt < 4; nt++) {
      int j = n0 + wn * 64 + nt * 16 + lr;
      size_t mrow = (size_t)m0 + wm * 32 + mt * 16 + lq * 4;
#pragma unroll
      for (int r = 0; r < 4; r++) {
        if constexpr (BF16OUT)
          ob[(size_t)bat * Ostr + (mrow + r) * 512 + j] = (bf16)acc[mt][nt][r];
        else
          of[(size_t)bat * Ostr + (mrow + r) * 512 + j] =
              acc[mt][nt][r] + (BIAS ? bja[nt] : 0.f);
      }
    }
}

// =====================================================================
// gemm_ox: out[tb] = bf16(x[tb]) * VT[tb]^T + cvec[tb]  (f32 out).
// BK=128 (4 K-steps); A reg-staged from f32 x (cvt in-flight, swizzled
// ds_write); B via gload_lds.
// =====================================================================
__global__ __launch_bounds__(256, 3)
void gemm_ox(const float* __restrict__ x, const bf16* __restrict__ VTb,
             const float* __restrict__ cvec, float* __restrict__ of) {
  constexpr int K = 512, PERB = 64;   // 16 m-tiles x 4 n-tiles
  const int bid = blockIdx.x;
  const int xcd = bid & 7, j9 = bid >> 3;
  const int bat = xcd + 8 * (j9 / PERB);
  const int tile = j9 % PERB;
  const int mi = tile >> 2, ni = tile & 3;
  const float* A = x + (size_t)bat * 524288;
  const bf16* Bt = VTb + (size_t)bat * 262144;
  const int m0 = mi * 64, n0 = ni * 128;
  __shared__ __align__(16) bf16 As[64][128];    // 16 KB
  __shared__ __align__(16) bf16 Bs[128][128];   // 32 KB
  const int tid = threadIdx.x, w = tid >> 6, l = tid & 63;
  const int wm = w >> 1, wn = w & 1;
  const int lr = l & 15, lq = l >> 4;
  const int srow = l >> 4, schk = l & 15;
  const int arow = tid >> 3;        // 0..31
  const int ac2 = (tid & 7) * 2;    // even chunk base
  f32x4 acc[2][4] = {};
  for (int kt = 0; kt < 4; kt++) {
    // ---- A: f32 -> bf16 reg-stage, swizzled ds_write (2 chunks/thread/row) --
#pragma unroll
    for (int i = 0; i < 2; i++) {
      int r = i * 32 + arow;
#pragma unroll
      for (int cc = 0; cc < 2; cc++) {
        int c = ac2 + cc;
        const float* src = A + (size_t)(m0 + r) * 512 + kt * 128 +
                           ((c ^ (r & 7)) * 8);
        float4 v0 = *(const float4*)(src);
        float4 v1 = *(const float4*)(src + 4);
        bf16x8 o;
        o[0]=(bf16)v0.x; o[1]=(bf16)v0.y; o[2]=(bf16)v0.z; o[3]=(bf16)v0.w;
        o[4]=(bf16)v1.x; o[5]=(bf16)v1.y; o[6]=(bf16)v1.z; o[7]=(bf16)v1.w;
        *(bf16x8*)&As[r][c * 8] = o;
      }
    }
    // ---- B: gload_lds ----
#pragma unroll
    for (int i = 0; i < 8; i++) {
      int rb = w * 32 + i * 4, r = rb + srow;
      gload16(Bt + (size_t)(n0 + r) * K + kt*128 + ((schk ^ (r & 7)) * 8),
              &Bs[rb][0]);
    }
    __syncthreads();
#pragma unroll
    for (int s = 0; s < 4; s++) {
      bf16x8 af[2], bv[4];
#pragma unroll
      for (int f = 0; f < 2; f++) {
        int ra = wm * 32 + f * 16 + lr;
        af[f] = *(const bf16x8*)&As[ra][((s*4+lq) ^ (ra & 7)) * 8];
      }
#pragma unroll
      for (int f = 0; f < 4; f++) {
        int rb2 = wn * 64 + f * 16 + lr;
        bv[f] = *(const bf16x8*)&Bs[rb2][((s*4+lq) ^ (rb2 & 7)) * 8];
      }
#pragma unroll
      for (int mt = 0; mt < 2; mt++)
#pragma unroll
        for (int nt = 0; nt < 4; nt++)
          acc[mt][nt] = __builtin_amdgcn_mfma_f32_16x16x32_bf16(
              af[mt], bv[nt], acc[mt][nt], 0, 0, 0);
    }
    __syncthreads();
  }

  float bja[4];
#pragma unroll
  for (int nt = 0; nt < 4; nt++) {
    int j = n0 + wn * 64 + nt * 16 + lr;
    bja[nt] = cvec[(size_t)bat * 512 + j];
  }
#pragma unroll
  for (int mt = 0; mt < 2; mt++)
#pragma unroll
    for (int nt = 0; nt < 4; nt++) {
      int j = n0 + wn * 64 + nt * 16 + lr;
      size_t mrow = (size_t)m0 + wm * 32 + mt * 16 + lq * 4;
#pragma unroll
      for (int r = 0; r < 4; r++)
        of[(size_t)bat * 524288 + (mrow + r) * 512 + j] = acc[mt][nt][r] + bja[nt];
    }
}

// =====================================================================
// gemm_vtc: blocks [0,1024): VT[tb] = ZT[tb]*WqT^T  (BK=128, 4 K-steps).
// blocks [1024,1056): cvec[tb][j] = bp'[j] + sum_h cpart[tb][h][j].
// =====================================================================
__global__ __launch_bounds__(256, 3)
void gemm_vtc(const bf16* __restrict__ ZT, const bf16* __restrict__ WqT,
              const float* __restrict__ BS, const float* __restrict__ cpart,
              bf16* __restrict__ VT, float* __restrict__ cvec) {
  constexpr int K = 512;
  const int tid = threadIdx.x;
  if (blockIdx.x >= 1024) {
    const int tb = blockIdx.x - 1024;
#pragma unroll
    for (int half = 0; half < 2; half++) {
      int j = tid + half * 256;
      float s = BS[1536 + j];
#pragma unroll
      for (int h = 0; h < 8; h++) s += cpart[(size_t)(tb * 8 + h) * 512 + j];
      cvec[tb * 512 + j] = s;
    }
    return;
  }
  const int bid = blockIdx.x;
  const int xcd = bid & 7, j9 = bid >> 3;
  const int bat = xcd + 8 * (j9 >> 5);
  const int tile = j9 & 31;
  const int mi = tile >> 2, ni = tile & 3;
  const bf16* A = ZT + (size_t)bat * 262144;
  const int m0 = mi * 64, n0 = ni * 128;
  __shared__ __align__(16) bf16 As[64][128];
  __shared__ __align__(16) bf16 Bs[128][128];
  const int w = tid >> 6, l = tid & 63;
  const int wm = w >> 1, wn = w & 1;
  const int lr = l & 15, lq = l >> 4;
  const int srow = l >> 4, schk = l & 15;
  f32x4 acc[2][4] = {};
  for (int kt = 0; kt < 4; kt++) {
#pragma unroll
    for (int i = 0; i < 4; i++) {
      int rb = w * 16 + i * 4, r = rb + srow;
      gload16(A + (size_t)(m0 + r) * K + kt*128 + ((schk ^ (r & 7)) * 8),
              &As[rb][0]);
    }
#pragma unroll
    for (int i = 0; i < 8; i++) {
      int rb = w * 32 + i * 4, r = rb + srow;
      gload16(WqT + (size_t)(n0 + r) * K + kt*128 + ((schk ^ (r & 7)) * 8),
              &Bs[rb][0]);
    }
    __syncthreads();
#pragma unroll
    for (int s = 0; s < 4; s++) {
      bf16x8 af[2], bv[4];
#pragma unroll
      for (int f = 0; f < 2; f++) {
        int ra = wm * 32 + f * 16 + lr;
        af[f] = *(const bf16x8*)&As[ra][((s*4+lq) ^ (ra & 7)) * 8];
      }
#pragma unroll
      for (int f = 0; f < 4; f++) {
        int rb2 = wn * 64 + f * 16 + lr;
        bv[f] = *(const bf16x8*)&Bs[rb2][((s*4+lq) ^ (rb2 & 7)) * 8];
      }
#pragma unroll
      for (int mt = 0; mt < 2; mt++)
#pragma unroll
        for (int nt = 0; nt < 4; nt++)
          acc[mt][nt] = __builtin_amdgcn_mfma_f32_16x16x32_bf16(
              af[mt], bv[nt], acc[mt][nt], 0, 0, 0);
    }
    __syncthreads();
  }
#pragma unroll
  for (int mt = 0; mt < 2; mt++)
#pragma unroll
    for (int nt = 0; nt < 4; nt++) {
      int j = n0 + wn * 64 + nt * 16 + lr;
      size_t mrow = (size_t)m0 + wm * 32 + mt * 16 + lq * 4;
#pragma unroll
      for (int r = 0; r < 4; r++)
        VT[(size_t)bat * 262144 + (mrow + r) * 512 + j] = (bf16)acc[mt][nt][r];
    }
}

// =====================================================================
// kvz (LDS-light): per (tb,h), wave w owns e-block [16w,16w+16), full K.
// =====================================================================
__global__ __launch_bounds__(256)
void kvz(const bf16* __restrict__ KGb, const bf16* __restrict__ WB,
         const float* __restrict__ BS, const float* __restrict__ ksv,
         bf16* __restrict__ ZT, float* __restrict__ cpart) {
  const int gid = blockIdx.x, tb = gid >> 3, h = gid & 7;
  const int t = threadIdx.x, w = t >> 6, l = t & 63;
  const int lr = l & 15, lq = l >> 4;
  __shared__ __align__(16) bf16 kvb[4096];   // [64][64] chunk-swizzled

  const bf16* KGrow = KGb + (size_t)tb * 262144 + (size_t)(64*h) * 512;
  const bf16* Vrow  = WB + 2u * 262144 + (size_t)(64*h) * 512;

  f32x4 acc2[4] = {};
  for (int ks = 0; ks < 16; ks++) {
    const int kc = ks * 32 + lq * 8;
    bf16x8 bv = *(const bf16x8*)(Vrow + (size_t)(w*16 + lr) * 512 + kc);
#pragma unroll
    for (int mf = 0; mf < 4; mf++) {
      bf16x8 af = *(const bf16x8*)(KGrow + (size_t)(mf*16 + lr) * 512 + kc);
      acc2[mf] = __builtin_amdgcn_mfma_f32_16x16x32_bf16(af, bv, acc2[mf], 0, 0, 0);
    }
  }
  {
    const float inv = 1.f / 1024.f;
    const int e = w * 16 + lr;
    const float vsh = ksv[16384 + tb * 512 + 64*h + e];
    const float bvh = BS[1024 + 64*h + e];
#pragma unroll
    for (int mf = 0; mf < 4; mf++)
#pragma unroll
      for (int r = 0; r < 4; r++) {
        int d = mf * 16 + lq * 4 + r;
        float ksh = ksv[tb * 512 + 64*h + d];
        float bkh = BS[512 + 64*h + d];
        float kv = (acc2[mf][r] + ksh * bvh + bkh * vsh) * inv + bkh * bvh;
        kvb[d * 64 + ((((e >> 3) ^ (d & 7)) * 8) + (e & 7))] = (bf16)kv;
      }
  }
  __syncthreads();

  f32x4 acc3[4][8] = {};
#pragma unroll
  for (int s = 0; s < 2; s++) {
    bf16x8 af3[4];
#pragma unroll
    for (int mf = 0; mf < 4; mf++) {
      int d = mf * 16 + lr;
      af3[mf] = *(const bf16x8*)&kvb[d * 64 + (((s*4+lq) ^ (d & 7)) * 8)];
    }
#pragma unroll
    for (int nf = 0; nf < 8; nf++) {
      int jj = w * 128 + nf * 16 + lr;
      bf16x8 b3 = *(const bf16x8*)(WB + 3u * 262144 + (size_t)jj * 512 +
                                   64*h + s * 32 + lq * 8);
#pragma unroll
      for (int mf = 0; mf < 4; mf++)
        acc3[mf][nf] = __builtin_amdgcn_mfma_f32_16x16x32_bf16(
            af3[mf], b3, acc3[mf][nf], 0, 0, 0);
    }
  }

  bf16* zbase = ZT + (size_t)tb * 262144 + 64*h;
#pragma unroll
  for (int nf = 0; nf < 8; nf++) {
    int jj = w * 128 + nf * 16 + lr;
    float cp = 0.f;
#pragma unroll
    for (int mf = 0; mf < 4; mf++) {
      bf16x4 o;
#pragma unroll
      for (int r = 0; r < 4; r++) {
        o[r] = (bf16)acc3[mf][nf][r];
        cp += acc3[mf][nf][r] * BS[64*h + mf*16 + lq*4 + r];
      }
      *(bf16x4*)(zbase + (size_t)jj * 512 + mf * 16 + lq * 4) = o;
    }
    cp += __shfl_xor(cp, 16);
    cp += __shfl_xor(cp, 32);
    if (lq == 0) cpart[(size_t)(tb * 8 + h) * 512 + jj] = cp;
  }
}

extern "C" void kernel_launch(void* const* d_in, const int* in_sizes, int n_in,
                              void* d_out, int out_size, void* d_ws, size_t ws_size,
                              hipStream_t stream) {
  const float* x = (const float*)d_in[0];
  char* ws = (char*)d_ws;
  bf16*  xT    = (bf16*)(ws + 33554432);      // [32][512][1024]
  bf16*  Gb    = (bf16*)(ws + 67108864);      // [32][512][512]
  bf16*  KGb   = (bf16*)(ws + 83886080);      // [32][512][512]
  bf16*  ZT    = (bf16*)(ws + 100663296);     // [32][512][512]
  bf16*  VT    = (bf16*)(ws + 117440512);     // [32][512][512]
  bf16*  WB    = (bf16*)(ws + 134217728);     // [4][512][512]
  bf16*  WqT   = (bf16*)(ws + 136314880);     // [512][512]
  float* BS    = (float*)(ws + 136839168);    // [4][512]
  float* ksv   = (float*)(ws + 136847360);    // [2][32][512]
  float* cpart = (float*)(ws + 136978432);    // [32][8][512]
  float* cvec  = (float*)(ws + 137502720);    // [32][512]
  float* spart = (float*)(ws + 137568256);    // [32*8*16][64]
  (void)in_sizes; (void)n_in; (void)out_size; (void)ws_size;

  PtrPack pk;
  for (int i = 0; i < 24; i++) pk.p[i] = (const float*)d_in[1 + i];

  cvt_prep<<<6208, 256, 0, stream>>>(pk, x, xT, spart, WB, BS, WqT);
  // SYM Gram (640 blocks) + ksvs (64 blocks)
  gram_ksvs<<<704, 256, 0, stream>>>(xT, WB, spart, Gb, ksv);
  // KG[tb] = K' * G[tb]
  gemm_n<4, 8, true, false><<<1024, 256, 0, stream>>>(
      WB + 262144, 0, Gb, 262144, nullptr, KGb, nullptr, 262144);
  kvz<<<256, 256, 0, stream>>>(KGb, WB, BS, ksv, ZT, cpart);
  // VT[tb] = ZT[tb] * WqT^T  (+ cvec finalization blocks)
  gemm_vtc<<<1056, 256, 0, stream>>>(ZT, WqT, BS, cpart, VT, cvec);
  // out[tb] = bf16(x[tb]) * VT[tb]^T + cvec[tb]  (f32 out, A from f32 x)
  gemm_ox<<<2048, 256, 0, stream>>>(x, VT, cvec, (float*)d_out);
}

// Round 14
// 127.657 us; speedup vs baseline: 1.0873x; 1.0873x over previous
//
#include <hip/hip_runtime.h>

#define T_ 4
#define B_ 8
#define N_ 1024
#define C_ 512
#define H_ 8
#define D_ 64
#define M_ (T_*B_*N_)   // 32768 rows
#define TB_ (T_*B_)     // 32

typedef __bf16 bf16;
typedef __bf16 bf16x4 __attribute__((ext_vector_type(4)));
typedef __bf16 bf16x8 __attribute__((ext_vector_type(8)));
typedef float f32x4 __attribute__((ext_vector_type(4)));

__device__ __forceinline__ void gload16(const void* g, void* l) {
  __builtin_amdgcn_global_load_lds(
      (const __attribute__((address_space(1))) void*)g,
      (__attribute__((address_space(3))) void*)l, 16, 0, 0);
}

struct PtrPack { const float* p[24]; };

// =====================================================================
// cvt_prep: blocks [0,4096): x -> xT (bf16 transpose) + col-sum partials.
// blocks [4096,6144): fold BN into the 4 weight mats (+ bias vec).
// blocks [6144,6208): WqT[c][d] = Wq[d][c]*sq[d].
// =====================================================================
__global__ __launch_bounds__(256)
void cvt_prep(PtrPack pk, const float* __restrict__ x,
              bf16* __restrict__ xT, float* __restrict__ spart,
              bf16* __restrict__ WB, float* __restrict__ BS,
              bf16* __restrict__ WqT) {
  const int t = threadIdx.x;
  __shared__ __align__(16) char smem[21120];   // 64*65 f32 + 16*64 f32
  if (blockIdx.x < 4096) {
    const int bid = blockIdx.x;
    const int tb = bid >> 7, nc = (bid >> 3) & 15, cc = bid & 7;
    float* lds = (float*)smem;                 // [64][65]
    float* sred = (float*)smem + 4160;         // [16][64]
    const float* xbase = x + (size_t)tb * 524288 + (size_t)nc * 64 * 512 + cc * 64;
    bf16* xTb = xT + (size_t)tb * 524288 + (size_t)(cc * 64) * 1024 + nc * 64;
    const int rgrp = t >> 4, k = t & 15;
    float s0 = 0, s1 = 0, s2 = 0, s3 = 0;
#pragma unroll
    for (int p = 0; p < 4; p++) {
      int r = p * 16 + rgrp;
      float4 v = *(const float4*)(xbase + (size_t)r * 512 + k * 4);
      lds[r*65 + k*4+0]=v.x; lds[r*65 + k*4+1]=v.y;
      lds[r*65 + k*4+2]=v.z; lds[r*65 + k*4+3]=v.w;
      s0 += v.x; s1 += v.y; s2 += v.z; s3 += v.w;
    }
    sred[rgrp*64 + k*4+0]=s0; sred[rgrp*64 + k*4+1]=s1;
    sred[rgrp*64 + k*4+2]=s2; sred[rgrp*64 + k*4+3]=s3;
    __syncthreads();
#pragma unroll
    for (int p = 0; p < 16; p++) {
      int c = p * 4 + (t >> 6), n = t & 63;
      xTb[(size_t)c * 1024 + n] = (bf16)lds[n*65 + c];
    }
    if (t < 64) {
      float tot = 0;
#pragma unroll
      for (int rg = 0; rg < 16; rg++) tot += sred[rg*64 + t];
      spart[(size_t)((tb*8 + cc)*16 + nc) * 64 + t] = tot;
    }
    return;
  }
  if (blockIdx.x < 6144) {
    const int e = blockIdx.x - 4096;
    const int mat = e >> 9, d = e & 511;
    const float* W    = pk.p[6*mat + 0];
    const float* b    = pk.p[6*mat + 1];
    const float* g    = pk.p[6*mat + 2];
    const float* beta = pk.p[6*mat + 3];
    const float* mu   = pk.p[6*mat + 4];
    const float* var  = pk.p[6*mat + 5];
    float s = g[d] * rsqrtf(var[d] + 1e-5f);
    if (t == 0) BS[mat*512 + d] = (b[d] - mu[d]) * s + beta[d];
    bf16* Wout = WB + (size_t)mat * 262144 + (size_t)d * 512;
    for (int c = t; c < 512; c += 256)
      Wout[c] = (bf16)(W[(size_t)d * 512 + c] * s);
    return;
  }
  // WqT part
  const int e = blockIdx.x - 6144;
  const int di = e >> 3, ci = e & 7;
  float* lds = (float*)smem;   // [64][65]
  const float* W = pk.p[0];
  const float* g = pk.p[2];
  const float* var = pk.p[5];
  const int rgrp = t >> 4, k = t & 15;
#pragma unroll
  for (int p = 0; p < 4; p++) {
    int r = p * 16 + rgrp;
    int d = di * 64 + r;
    float s = g[d] * rsqrtf(var[d] + 1e-5f);
    float4 v = *(const float4*)(W + (size_t)d * 512 + ci * 64 + k * 4);
    lds[r*65 + k*4+0] = v.x * s; lds[r*65 + k*4+1] = v.y * s;
    lds[r*65 + k*4+2] = v.z * s; lds[r*65 + k*4+3] = v.w * s;
  }
  __syncthreads();
#pragma unroll
  for (int p = 0; p < 16; p++) {
    int c = p * 4 + (t >> 6), dd = t & 63;
    WqT[(size_t)(ci*64 + c) * 512 + di*64 + dd] = (bf16)lds[dd*65 + c];
  }
}

// =====================================================================
// gram_ksvs: blocks [0,640): SYM Gram G[tb] = xT xT^T with 64x128 tiles,
//   BK=64, triangular 20/32 set, mirror-store via swizzled LDS bounce.
// blocks [640,704): ksvs.
// =====================================================================
__global__ __launch_bounds__(256)
void gram_ksvs(const bf16* __restrict__ xT, const bf16* __restrict__ WB,
               const float* __restrict__ spart, bf16* __restrict__ Gb,
               float* __restrict__ ksv) {
  const int t = threadIdx.x;
  __shared__ __align__(16) char smem[24576];
  if (blockIdx.x >= 640) {
    const int e = blockIdx.x - 640, tb = e >> 1, m = e & 1;
    float* sl = (float*)smem;
#pragma unroll
    for (int half = 0; half < 2; half++) {
      int c = t + half * 256, cc = c >> 6, cl = c & 63;
      float tot = 0;
#pragma unroll
      for (int ncf = 0; ncf < 16; ncf++)
        tot += spart[(size_t)((tb*8 + cc)*16 + ncf) * 64 + cl];
      sl[c] = tot;
    }
    __syncthreads();
#pragma unroll
    for (int half = 0; half < 2; half++) {
      int d = t + half * 256;
      const bf16* Wrow = WB + (size_t)(m + 1) * 262144 + (size_t)d * 512;
      float acc = 0;
      for (int k = 0; k < 512; k += 8) {
        bf16x8 wv = *(const bf16x8*)(Wrow + k);
#pragma unroll
        for (int i = 0; i < 8; i++) acc += (float)wv[i] * sl[k + i];
      }
      ksv[m * 16384 + tb * 512 + d] = acc;
    }
    return;
  }
  constexpr int K = 1024;
  const int bid = blockIdx.x;
  const int xcd = bid & 7, j9 = bid >> 3;
  const int bat = xcd + 8 * (j9 / 20);
  const int tile = j9 % 20;
  int mi, ni;
  if (tile < 8)       { mi = tile;          ni = 0; }
  else if (tile < 14) { mi = tile - 8 + 2;  ni = 1; }
  else if (tile < 18) { mi = tile - 14 + 4; ni = 2; }
  else                { mi = tile - 18 + 6; ni = 3; }
  const bf16* A = xT + (size_t)bat * 524288;
  const int m0 = mi * 64, n0 = ni * 128;
  bf16* As = (bf16*)smem;
  bf16* Bs = (bf16*)(smem + 8192);
  const int w = t >> 6, l = t & 63;
  const int wm = w >> 1, wn = w & 1;
  const int lr = l & 15, lq = l >> 4, l7 = l & 7, lh = l >> 3;
  const int srcc = (l7 ^ lh) * 8;
  f32x4 acc[2][4] = {};
  for (int kt = 0; kt < 16; kt++) {
#pragma unroll
    for (int i = 0; i < 2; i++) {
      int rb = w * 16 + i * 8;
      gload16(A + (size_t)(m0 + rb + lh) * K + kt * 64 + srcc, &As[rb * 64]);
    }
#pragma unroll
    for (int i = 0; i < 4; i++) {
      int rb = w * 32 + i * 8;
      gload16(A + (size_t)(n0 + rb + lh) * K + kt * 64 + srcc, &Bs[rb * 64]);
    }
    __syncthreads();
    bf16x8 af[2][2], bv[4][2];
#pragma unroll
    for (int f = 0; f < 2; f++) {
      int ra = wm * 32 + f * 16 + lr;
#pragma unroll
      for (int s = 0; s < 2; s++)
        af[f][s] = *(const bf16x8*)&As[ra * 64 + (((s*4+lq) ^ (ra & 7)) * 8)];
    }
#pragma unroll
    for (int f = 0; f < 4; f++) {
      int rb2 = wn * 64 + f * 16 + lr;
#pragma unroll
      for (int s = 0; s < 2; s++)
        bv[f][s] = *(const bf16x8*)&Bs[rb2 * 64 + (((s*4+lq) ^ (rb2 & 7)) * 8)];
    }
#pragma unroll
    for (int mt = 0; mt < 2; mt++)
#pragma unroll
      for (int nt = 0; nt < 4; nt++)
#pragma unroll
        for (int s = 0; s < 2; s++)
          acc[mt][nt] = __builtin_amdgcn_mfma_f32_16x16x32_bf16(
              af[mt][s], bv[nt][s], acc[mt][nt], 0, 0, 0);
    __syncthreads();
  }
  bf16* ob = Gb + (size_t)bat * 262144;
#pragma unroll
  for (int mt = 0; mt < 2; mt++)
#pragma unroll
    for (int nt = 0; nt < 4; nt++) {
      int j = n0 + wn * 64 + nt * 16 + lr;
      size_t mrow = (size_t)m0 + wm * 32 + mt * 16 + lq * 4;
#pragma unroll
      for (int r = 0; r < 4; r++)
        ob[(mrow + r) * 512 + j] = (bf16)acc[mt][nt][r];
    }
  bf16* TB = (bf16*)smem;
#pragma unroll
  for (int mt = 0; mt < 2; mt++)
#pragma unroll
    for (int nt = 0; nt < 4; nt++) {
      int a = wn * 64 + nt * 16 + lr;
#pragma unroll
      for (int r = 0; r < 4; r++) {
        int b = wm * 32 + mt * 16 + lq * 4 + r;
        TB[(a * 64 + b) ^ ((a & 7) << 3)] = (bf16)acc[mt][nt][r];
      }
    }
  __syncthreads();
  const int rowa = t >> 1, half = t & 1;
#pragma unroll
  for (int i = 0; i < 4; i++) {
    int c8 = half * 4 + i;
    bf16x8 v = *(const bf16x8*)&TB[(rowa * 64 + c8 * 8) ^ ((rowa & 7) << 3)];
    *(bf16x8*)(ob + (size_t)(n0 + rowa) * 512 + m0 + c8 * 8) = v;
  }
}

// =====================================================================
// Batched 64x128-tile GEMM, BK=64, 24 KB LDS single-buffered,
// chunk-XOR swizzle, gload_lds staging, XCD-clustered batches.
// =====================================================================
template <int NKT, int MTILES, bool BF16OUT, bool BIAS>
__global__ __launch_bounds__(256, 6)
void gemm_n(const bf16* __restrict__ Abase, size_t Astr,
            const bf16* __restrict__ Btbase, size_t Btstr,
            const float* __restrict__ BSb,
            bf16* __restrict__ ob, float* __restrict__ of, size_t Ostr) {
  constexpr int K = NKT * 64;
  constexpr int PERB = MTILES * 4;
  const int bid = blockIdx.x;
  const int xcd = bid & 7, j9 = bid >> 3;
  const int bat = xcd + 8 * (j9 / PERB);
  const int tile = j9 % PERB;
  const int mi = tile >> 2, ni = tile & 3;
  const bf16* A = Abase + (size_t)bat * Astr;
  const bf16* Bt = Btbase + (size_t)bat * Btstr;
  const int m0 = mi * 64, n0 = ni * 128;
  __shared__ __align__(16) bf16 As[64][64];
  __shared__ __align__(16) bf16 Bs[128][64];
  const int tid = threadIdx.x, w = tid >> 6, l = tid & 63;
  const int wm = w >> 1, wn = w & 1;
  const int lr = l & 15, lq = l >> 4, l7 = l & 7, lh = l >> 3;
  const int srcc = (l7 ^ lh) * 8;
  f32x4 acc[2][4] = {};
  for (int kt = 0; kt < NKT; kt++) {
#pragma unroll
    for (int i = 0; i < 2; i++) {
      int rb = w * 16 + i * 8;
      gload16(A + (size_t)(m0 + rb + lh) * K + kt * 64 + srcc, &As[rb][0]);
    }
#pragma unroll
    for (int i = 0; i < 4; i++) {
      int rb = w * 32 + i * 8;
      gload16(Bt + (size_t)(n0 + rb + lh) * K + kt * 64 + srcc, &Bs[rb][0]);
    }
    __syncthreads();
    bf16x8 af[2][2], bv[4][2];
#pragma unroll
    for (int f = 0; f < 2; f++) {
      int ra = wm * 32 + f * 16 + lr;
#pragma unroll
      for (int s = 0; s < 2; s++)
        af[f][s] = *(const bf16x8*)&As[ra][((s*4+lq) ^ (ra & 7)) * 8];
    }
#pragma unroll
    for (int f = 0; f < 4; f++) {
      int rb2 = wn * 64 + f * 16 + lr;
#pragma unroll
      for (int s = 0; s < 2; s++)
        bv[f][s] = *(const bf16x8*)&Bs[rb2][((s*4+lq) ^ (rb2 & 7)) * 8];
    }
#pragma unroll
    for (int mt = 0; mt < 2; mt++)
#pragma unroll
      for (int nt = 0; nt < 4; nt++)
#pragma unroll
        for (int s = 0; s < 2; s++)
          acc[mt][nt] = __builtin_amdgcn_mfma_f32_16x16x32_bf16(
              af[mt][s], bv[nt][s], acc[mt][nt], 0, 0, 0);
    __syncthreads();
  }

  float bja[4];
  if constexpr (BIAS) {
#pragma unroll
    for (int nt = 0; nt < 4; nt++) {
      int j = n0 + wn * 64 + nt * 16 + lr;
      bja[nt] = BSb[(size_t)bat * 512 + j];
    }
  }
#pragma unroll
  for (int mt = 0; mt < 2; mt++)
#pragma unroll
    for (int nt = 0; nt < 4; nt++) {
      int j = n0 + wn * 64 + nt * 16 + lr;
      size_t mrow = (size_t)m0 + wm * 32 + mt * 16 + lq * 4;
#pragma unroll
      for (int r = 0; r < 4; r++) {
        if constexpr (BF16OUT)
          ob[(size_t)bat * Ostr + (mrow + r) * 512 + j] = (bf16)acc[mt][nt][r];
        else
          of[(size_t)bat * Ostr + (mrow + r) * 512 + j] =
              acc[mt][nt][r] + (BIAS ? bja[nt] : 0.f);
      }
    }
}

// =====================================================================
// gemm_ox: out[tb] = bf16(x[tb]) * VT[tb]^T + cvec[tb]  (f32 out).
// 64x256 tile (2 n-tiles/block: staged A amortized 2x), BK=64,
// A reg-staged from f32 x (r12's verified linear-src/swizzled-dest),
// B via gload_lds.  LDS 40 KB -> 4 blocks/CU cap.
// =====================================================================
__global__ __launch_bounds__(256, 3)
void gemm_ox(const float* __restrict__ x, const bf16* __restrict__ VTb,
             const float* __restrict__ cvec, float* __restrict__ of) {
  constexpr int K = 512, NKT = 8, PERB = 32;   // 16 m-tiles x 2 n-tiles
  const int bid = blockIdx.x;
  const int xcd = bid & 7, j9 = bid >> 3;
  const int bat = xcd + 8 * (j9 / PERB);
  const int tile = j9 % PERB;
  const int mi = tile >> 1, ni = tile & 1;
  const float* A = x + (size_t)bat * 524288;
  const bf16* Bt = VTb + (size_t)bat * 262144;
  const int m0 = mi * 64, n0 = ni * 256;
  __shared__ __align__(16) bf16 As[64][64];    //  8 KB
  __shared__ __align__(16) bf16 Bs[256][64];   // 32 KB
  const int tid = threadIdx.x, w = tid >> 6, l = tid & 63;
  const int wm = w >> 1, wn = w & 1;
  const int lr = l & 15, lq = l >> 4, l7 = l & 7, lh = l >> 3;
  const int srcc = (l7 ^ lh) * 8;
  const int ach = tid & 7;          // A-staging: chunk 0..7
  const int arow = tid >> 3;        // A-staging: row 0..31 (+32)
  f32x4 acc[2][8] = {};
  for (int kt = 0; kt < NKT; kt++) {
    // ---- A: f32 -> bf16 reg-stage, linear global src, swizzled ds_write ----
#pragma unroll
    for (int i = 0; i < 2; i++) {
      int r = i * 32 + arow;
      const float* src = A + (size_t)(m0 + r) * 512 + kt * 64 + ach * 8;
      float4 v0 = *(const float4*)(src);
      float4 v1 = *(const float4*)(src + 4);
      bf16x8 o;
      o[0]=(bf16)v0.x; o[1]=(bf16)v0.y; o[2]=(bf16)v0.z; o[3]=(bf16)v0.w;
      o[4]=(bf16)v1.x; o[5]=(bf16)v1.y; o[6]=(bf16)v1.z; o[7]=(bf16)v1.w;
      *(bf16x8*)&As[r][((ach ^ (r & 7)) * 8)] = o;
    }
    // ---- B: gload_lds, 256 rows ----
#pragma unroll
    for (int i = 0; i < 8; i++) {
      int rb = w * 64 + i * 8;
      gload16(Bt + (size_t)(n0 + rb + lh) * K + kt * 64 + srcc, &Bs[rb][0]);
    }
    __syncthreads();
    bf16x8 af[2][2];
#pragma unroll
    for (int f = 0; f < 2; f++) {
      int ra = wm * 32 + f * 16 + lr;
#pragma unroll
      for (int s = 0; s < 2; s++)
        af[f][s] = *(const bf16x8*)&As[ra][((s*4+lq) ^ (ra & 7)) * 8];
    }
#pragma unroll
    for (int s = 0; s < 2; s++) {
#pragma unroll
      for (int nt = 0; nt < 8; nt++) {
        int rb2 = wn * 128 + nt * 16 + lr;
        bf16x8 bv = *(const bf16x8*)&Bs[rb2][((s*4+lq) ^ (rb2 & 7)) * 8];
#pragma unroll
        for (int mt = 0; mt < 2; mt++)
          acc[mt][nt] = __builtin_amdgcn_mfma_f32_16x16x32_bf16(
              af[mt][s], bv, acc[mt][nt], 0, 0, 0);
      }
    }
    __syncthreads();
  }

  float bja[8];
#pragma unroll
  for (int nt = 0; nt < 8; nt++) {
    int j = n0 + wn * 128 + nt * 16 + lr;
    bja[nt] = cvec[(size_t)bat * 512 + j];
  }
#pragma unroll
  for (int mt = 0; mt < 2; mt++)
#pragma unroll
    for (int nt = 0; nt < 8; nt++) {
      int j = n0 + wn * 128 + nt * 16 + lr;
      size_t mrow = (size_t)m0 + wm * 32 + mt * 16 + lq * 4;
#pragma unroll
      for (int r = 0; r < 4; r++)
        of[(size_t)bat * 524288 + (mrow + r) * 512 + j] = acc[mt][nt][r] + bja[nt];
    }
}

// =====================================================================
// gemm_vtc: blocks [0,1024): VT[tb] = ZT[tb]*WqT^T  (64x128 tiles, K=512).
// blocks [1024,1056): cvec[tb][j] = bp'[j] + sum_h cpart[tb][h][j].
// =====================================================================
__global__ __launch_bounds__(256, 6)
void gemm_vtc(const bf16* __restrict__ ZT, const bf16* __restrict__ WqT,
              const float* __restrict__ BS, const float* __restrict__ cpart,
              bf16* __restrict__ VT, float* __restrict__ cvec) {
  constexpr int K = 512;
  const int tid = threadIdx.x;
  if (blockIdx.x >= 1024) {
    const int tb = blockIdx.x - 1024;
#pragma unroll
    for (int half = 0; half < 2; half++) {
      int j = tid + half * 256;
      float s = BS[1536 + j];
#pragma unroll
      for (int h = 0; h < 8; h++) s += cpart[(size_t)(tb * 8 + h) * 512 + j];
      cvec[tb * 512 + j] = s;
    }
    return;
  }
  const int bid = blockIdx.x;
  const int xcd = bid & 7, j9 = bid >> 3;
  const int bat = xcd + 8 * (j9 >> 5);
  const int tile = j9 & 31;
  const int mi = tile >> 2, ni = tile & 3;
  const bf16* A = ZT + (size_t)bat * 262144;
  const int m0 = mi * 64, n0 = ni * 128;
  __shared__ __align__(16) bf16 As[64][64];
  __shared__ __align__(16) bf16 Bs[128][64];
  const int w = tid >> 6, l = tid & 63;
  const int wm = w >> 1, wn = w & 1;
  const int lr = l & 15, lq = l >> 4, l7 = l & 7, lh = l >> 3;
  const int srcc = (l7 ^ lh) * 8;
  f32x4 acc[2][4] = {};
  for (int kt = 0; kt < 8; kt++) {
#pragma unroll
    for (int i = 0; i < 2; i++) {
      int rb = w * 16 + i * 8;
      gload16(A + (size_t)(m0 + rb + lh) * K + kt * 64 + srcc, &As[rb][0]);
    }
#pragma unroll
    for (int i = 0; i < 4; i++) {
      int rb = w * 32 + i * 8;
      gload16(WqT + (size_t)(n0 + rb + lh) * K + kt * 64 + srcc, &Bs[rb][0]);
    }
    __syncthreads();
    bf16x8 af[2][2], bv[4][2];
#pragma unroll
    for (int f = 0; f < 2; f++) {
      int ra = wm * 32 + f * 16 + lr;
#pragma unroll
      for (int s = 0; s < 2; s++)
        af[f][s] = *(const bf16x8*)&As[ra][((s*4+lq) ^ (ra & 7)) * 8];
    }
#pragma unroll
    for (int f = 0; f < 4; f++) {
      int rb2 = wn * 64 + f * 16 + lr;
#pragma unroll
      for (int s = 0; s < 2; s++)
        bv[f][s] = *(const bf16x8*)&Bs[rb2][((s*4+lq) ^ (rb2 & 7)) * 8];
    }
#pragma unroll
    for (int mt = 0; mt < 2; mt++)
#pragma unroll
      for (int nt = 0; nt < 4; nt++)
#pragma unroll
        for (int s = 0; s < 2; s++)
          acc[mt][nt] = __builtin_amdgcn_mfma_f32_16x16x32_bf16(
              af[mt][s], bv[nt][s], acc[mt][nt], 0, 0, 0);
    __syncthreads();
  }
#pragma unroll
  for (int mt = 0; mt < 2; mt++)
#pragma unroll
    for (int nt = 0; nt < 4; nt++) {
      int j = n0 + wn * 64 + nt * 16 + lr;
      size_t mrow = (size_t)m0 + wm * 32 + mt * 16 + lq * 4;
#pragma unroll
      for (int r = 0; r < 4; r++)
        VT[(size_t)bat * 262144 + (mrow + r) * 512 + j] = (bf16)acc[mt][nt][r];
    }
}

// =====================================================================
// kvz (LDS-light): per (tb,h), wave w owns e-block [16w,16w+16), full K.
// =====================================================================
__global__ __launch_bounds__(256)
void kvz(const bf16* __restrict__ KGb, const bf16* __restrict__ WB,
         const float* __restrict__ BS, const float* __restrict__ ksv,
         bf16* __restrict__ ZT, float* __restrict__ cpart) {
  const int gid = blockIdx.x, tb = gid >> 3, h = gid & 7;
  const int t = threadIdx.x, w = t >> 6, l = t & 63;
  const int lr = l & 15, lq = l >> 4;
  __shared__ __align__(16) bf16 kvb[4096];   // [64][64] chunk-swizzled

  const bf16* KGrow = KGb + (size_t)tb * 262144 + (size_t)(64*h) * 512;
  const bf16* Vrow  = WB + 2u * 262144 + (size_t)(64*h) * 512;

  f32x4 acc2[4] = {};
  for (int ks = 0; ks < 16; ks++) {
    const int kc = ks * 32 + lq * 8;
    bf16x8 bv = *(const bf16x8*)(Vrow + (size_t)(w*16 + lr) * 512 + kc);
#pragma unroll
    for (int mf = 0; mf < 4; mf++) {
      bf16x8 af = *(const bf16x8*)(KGrow + (size_t)(mf*16 + lr) * 512 + kc);
      acc2[mf] = __builtin_amdgcn_mfma_f32_16x16x32_bf16(af, bv, acc2[mf], 0, 0, 0);
    }
  }
  {
    const float inv = 1.f / 1024.f;
    const int e = w * 16 + lr;
    const float vsh = ksv[16384 + tb * 512 + 64*h + e];
    const float bvh = BS[1024 + 64*h + e];
#pragma unroll
    for (int mf = 0; mf < 4; mf++)
#pragma unroll
      for (int r = 0; r < 4; r++) {
        int d = mf * 16 + lq * 4 + r;
        float ksh = ksv[tb * 512 + 64*h + d];
        float bkh = BS[512 + 64*h + d];
        float kv = (acc2[mf][r] + ksh * bvh + bkh * vsh) * inv + bkh * bvh;
        kvb[d * 64 + ((((e >> 3) ^ (d & 7)) * 8) + (e & 7))] = (bf16)kv;
      }
  }
  __syncthreads();

  f32x4 acc3[4][8] = {};
#pragma unroll
  for (int s = 0; s < 2; s++) {
    bf16x8 af3[4];
#pragma unroll
    for (int mf = 0; mf < 4; mf++) {
      int d = mf * 16 + lr;
      af3[mf] = *(const bf16x8*)&kvb[d * 64 + (((s*4+lq) ^ (d & 7)) * 8)];
    }
#pragma unroll
    for (int nf = 0; nf < 8; nf++) {
      int jj = w * 128 + nf * 16 + lr;
      bf16x8 b3 = *(const bf16x8*)(WB + 3u * 262144 + (size_t)jj * 512 +
                                   64*h + s * 32 + lq * 8);
#pragma unroll
      for (int mf = 0; mf < 4; mf++)
        acc3[mf][nf] = __builtin_amdgcn_mfma_f32_16x16x32_bf16(
            af3[mf], b3, acc3[mf][nf], 0, 0, 0);
    }
  }

  bf16* zbase = ZT + (size_t)tb * 262144 + 64*h;
#pragma unroll
  for (int nf = 0; nf < 8; nf++) {
    int jj = w * 128 + nf * 16 + lr;
    float cp = 0.f;
#pragma unroll
    for (int mf = 0; mf < 4; mf++) {
      bf16x4 o;
#pragma unroll
      for (int r = 0; r < 4; r++) {
        o[r] = (bf16)acc3[mf][nf][r];
        cp += acc3[mf][nf][r] * BS[64*h + mf*16 + lq*4 + r];
      }
      *(bf16x4*)(zbase + (size_t)jj * 512 + mf * 16 + lq * 4) = o;
    }
    cp += __shfl_xor(cp, 16);
    cp += __shfl_xor(cp, 32);
    if (lq == 0) cpart[(size_t)(tb * 8 + h) * 512 + jj] = cp;
  }
}

extern "C" void kernel_launch(void* const* d_in, const int* in_sizes, int n_in,
                              void* d_out, int out_size, void* d_ws, size_t ws_size,
                              hipStream_t stream) {
  const float* x = (const float*)d_in[0];
  char* ws = (char*)d_ws;
  bf16*  xT    = (bf16*)(ws + 33554432);      // [32][512][1024]
  bf16*  Gb    = (bf16*)(ws + 67108864);      // [32][512][512]
  bf16*  KGb   = (bf16*)(ws + 83886080);      // [32][512][512]
  bf16*  ZT    = (bf16*)(ws + 100663296);     // [32][512][512]
  bf16*  VT    = (bf16*)(ws + 117440512);     // [32][512][512]
  bf16*  WB    = (bf16*)(ws + 134217728);     // [4][512][512]
  bf16*  WqT   = (bf16*)(ws + 136314880);     // [512][512]
  float* BS    = (float*)(ws + 136839168);    // [4][512]
  float* ksv   = (float*)(ws + 136847360);    // [2][32][512]
  float* cpart = (float*)(ws + 136978432);    // [32][8][512]
  float* cvec  = (float*)(ws + 137502720);    // [32][512]
  float* spart = (float*)(ws + 137568256);    // [32*8*16][64]
  (void)in_sizes; (void)n_in; (void)out_size; (void)ws_size;

  PtrPack pk;
  for (int i = 0; i < 24; i++) pk.p[i] = (const float*)d_in[1 + i];

  cvt_prep<<<6208, 256, 0, stream>>>(pk, x, xT, spart, WB, BS, WqT);
  // SYM Gram (640 blocks) + ksvs (64 blocks)
  gram_ksvs<<<704, 256, 0, stream>>>(xT, WB, spart, Gb, ksv);
  // KG[tb] = K' * G[tb]
  gemm_n<8, 8, true, false><<<1024, 256, 0, stream>>>(
      WB + 262144, 0, Gb, 262144, nullptr, KGb, nullptr, 262144);
  kvz<<<256, 256, 0, stream>>>(KGb, WB, BS, ksv, ZT, cpart);
  // VT[tb] = ZT[tb] * WqT^T  (+ cvec finalization blocks)
  gemm_vtc<<<1056, 256, 0, stream>>>(ZT, WqT, BS, cpart, VT, cvec);
  // out[tb] = bf16(x[tb]) * VT[tb]^T + cvec[tb]  (f32 out, 64x256 tiles)
  gemm_ox<<<1024, 256, 0, stream>>>(x, VT, cvec, (float*)d_out);
}